// Round 1
// baseline (634.015 us; speedup 1.0000x reference)
//
#include <hip/hip_runtime.h>
#include <cstdint>
#include <cstddef>

// DimensionPruning: per-dim BH-FDR rejection count.
// importance[d] = #{m in [1,n]: C_d(m) >= m} + min{m: C_d(m) >= m} - 1  (0 if none)
// where C_d(m) = #{i: u_i <= m}, u_i = ceil(p_i * n/alpha), p_i = Phi(-mu/sigma).
//
// Fused design: pass 1 computes u per element and atomically increments
// hist[dim][u-1] in the global workspace (only ~15% of elements have u != 0).
// This removes the 100 MB transposed-u16 intermediate (written with 2x
// amplification, re-read by a latency-bound pass) and the 8-way LDS-conflict
// transpose of the previous version.
//
// erfcf gate (bit-exact vs. the previous passing kernel):
//   x = mu/var < 2   -> s = p*2e6 >= 45500 > 15360  -> u = 0   (both paths)
//   x > 6            -> p <= 1e-9 -> s <= 2e-3 -> ceil->clamp -> u = 1 (both)
//   2 <= x <= 6      -> identical fp sequence to the old kernel.

#define N_OBJ  100000
#define N_DIM  512
#define UCAP   15360          // bins m = 1..UCAP; u = 0 means discarded

// ---------------- pass 0: zero the histograms ----------------
__global__ __launch_bounds__(256) void zero_kernel(uint4* __restrict__ p, int n4)
{
    const int i = blockIdx.x * 256 + threadIdx.x;
    if (i < n4) p[i] = make_uint4(0u, 0u, 0u, 0u);
}

// ---------------- pass 1: u + global-atomic histogram ----------------
__global__ __launch_bounds__(256) void u_hist_kernel(
    const float* __restrict__ mu, const float* __restrict__ var,
    unsigned int* __restrict__ hist, int c0, int dc, int nslots)
{
    const int slot = blockIdx.x * 256 + threadIdx.x;
    if (slot >= nslots) return;
    const int qpr = dc >> 2;                   // float4 slots per row chunk
    const int r   = slot / qpr;
    const int dl  = (slot - r * qpr) << 2;     // local dim 0..dc-4
    const size_t off = (size_t)r * N_DIM + c0 + dl;
    const float4 m4 = *(const float4*)(mu + off);
    const float4 v4 = *(const float4*)(var + off);
    const float ms[4] = {m4.x, m4.y, m4.z, m4.w};
    const float vs[4] = {v4.x, v4.y, v4.z, v4.w};

    #pragma unroll
    for (int j = 0; j < 4; ++j) {
        const float m = ms[j], v = vs[j];
        if (m < 2.0f * v) continue;            // x < 2  -> u = 0
        unsigned int u;
        if (m > 6.0f * v) {
            u = 1u;                            // x > 6  -> u = 1
        } else {
            const float x = m / v;
            const float p = 0.5f * erfcf(x * 0.70710678118654752f);
            const float s = p * 2000000.0f;    // p * n / alpha
            if (s <= (float)UCAP) {
                const int ui = (int)ceilf(s);
                u = (unsigned int)(ui < 1 ? 1 : ui);   // underflow -> bin 1
            } else {
                u = 0u;
            }
        }
        if (u) atomicAdd(&hist[(size_t)(dl + j) * UCAP + (u - 1u)], 1u);
    }
}

// ---------------- pass 2: per-dim cumulative scan of hist ----------------
__global__ __launch_bounds__(256) void scan_kernel(
    const unsigned int* __restrict__ hist, int* __restrict__ out, int c0)
{
    __shared__ unsigned int wsum[4];
    __shared__ unsigned int redc[4], redm[4];
    const int tid  = threadIdx.x;
    const int lane = tid & 63;
    const int wid  = tid >> 6;
    const unsigned int* __restrict__ h = hist + (size_t)blockIdx.x * UCAP;

    unsigned int running = 0, tcount = 0, tmin = 0xFFFFFFFFu;
    uint4 c = *(const uint4*)&h[tid << 2];     // prefetched current chunk
    for (int u0 = 0; u0 < UCAP; u0 += 1024) {
        // prefetch next chunk while scanning this one
        uint4 cn = make_uint4(0u, 0u, 0u, 0u);
        const int nidx = u0 + 1024 + (tid << 2);
        if (nidx < UCAP) cn = *(const uint4*)&h[nidx];

        const int idx = u0 + (tid << 2);
        const unsigned int ls = c.x + c.y + c.z + c.w;

        unsigned int sc = ls;                  // wave64 inclusive scan
        #pragma unroll
        for (int dd = 1; dd < 64; dd <<= 1) {
            const unsigned int vv = __shfl_up(sc, dd, 64);
            if (lane >= dd) sc += vv;
        }
        if (lane == 63) wsum[wid] = sc;
        __syncthreads();

        unsigned int woff = 0, btot = 0;
        #pragma unroll
        for (int w = 0; w < 4; ++w) {
            const unsigned int s = wsum[w];
            btot += s;
            if (w < wid) woff += s;
        }

        unsigned int P = running + woff + (sc - ls);   // exclusive prefix
        const unsigned int cc[4] = {c.x, c.y, c.z, c.w};
        #pragma unroll
        for (int j = 0; j < 4; ++j) {
            P += cc[j];                                // inclusive C(m), m = idx+j+1
            const unsigned int mm = (unsigned int)(idx + j + 1);
            if (P >= mm) { tcount++; if (mm < tmin) tmin = mm; }
        }
        running += btot;
        __syncthreads();
        c = cn;
    }

    #pragma unroll
    for (int d = 32; d > 0; d >>= 1) {
        tcount += __shfl_down(tcount, d, 64);
        const unsigned int om = __shfl_down(tmin, d, 64);
        if (om < tmin) tmin = om;
    }
    if (lane == 0) { redc[wid] = tcount; redm[wid] = tmin; }
    __syncthreads();
    if (tid == 0) {
        const unsigned int tot = redc[0] + redc[1] + redc[2] + redc[3];
        const unsigned int mn  = min(min(redm[0], redm[1]), min(redm[2], redm[3]));
        out[c0 + blockIdx.x] = tot ? (int)(tot + mn - 1u) : 0;
    }
}

extern "C" void kernel_launch(void* const* d_in, const int* in_sizes, int n_in,
                              void* d_out, int out_size, void* d_ws, size_t ws_size,
                              hipStream_t stream)
{
    const float* mu  = (const float*)d_in[0];
    const float* var = (const float*)d_in[1];
    int* out = (int*)d_out;
    unsigned int* hist = (unsigned int*)d_ws;

    // chunk over dims if ws can't hold all 512 histograms (needs 31.5 MB)
    int D_c = N_DIM;
    while ((size_t)D_c * UCAP * sizeof(unsigned int) > ws_size && D_c > 4) D_c >>= 1;

    for (int c0 = 0; c0 < N_DIM; c0 += D_c) {
        const int n4 = D_c * UCAP / 4;
        zero_kernel<<<(n4 + 255) / 256, 256, 0, stream>>>((uint4*)hist, n4);
        const int nslots = N_OBJ * (D_c / 4);
        u_hist_kernel<<<(nslots + 255) / 256, 256, 0, stream>>>(
            mu, var, hist, c0, D_c, nslots);
        scan_kernel<<<D_c, 256, 0, stream>>>(hist, out, c0);
    }
}